// Round 1
// baseline (309.208 us; speedup 1.0000x reference)
//
#include <hip/hip_runtime.h>

#define TT 512
#define BB 64
#define DD 1024
#define KK 32

__device__ __forceinline__ float rfl(float v) {
  return __int_as_float(__builtin_amdgcn_readfirstlane(__float_as_int(v)));
}

// ---------------------------------------------------------------------------
// Kernel 1: emission.  F[m,k] = exp( x[m,:] @ W[:,k] + b[k] ).
// r6 re-tile for occupancy: grid 2048 x 256 thr -> 8 blocks/CU, 32 waves/CU
// (100%), up from 2 blocks/CU / 19.6% in r5.  Block = 16 rows; wave w =
// d-quarter [256w, 256w+256).  Lane tile: 1 row (rg=l>>2) x 8 k (kg=l&3)
// -> acc[8].  W staged per-wave in 4 KB chunks (32 d x 32 k), register-
// prefetched one chunk ahead to hide L2 latency; wave-local, no barrier.
// LDS 16 KB/block (8 blocks x 16 KB = 128 KB/CU).  x double-buffered
// (depth-1) float4 loads; 8 waves/SIMD provide TLP for HBM latency.
// __launch_bounds__(256,8): ~52 live VGPRs estimated, cap 64 is safe with
// the slim acc[8] tile (r5's spills were the acc[4][8]+pw[8] structure).
// ---------------------------------------------------------------------------
__global__ __launch_bounds__(256, 8) void emit_kernel(
    const float* __restrict__ x, const float* __restrict__ W,
    const float* __restrict__ bias, float* __restrict__ F) {
  __shared__ float4 Ls4[1024];           // 16 KB: 4 waves x 256 f4 W chunk
  const int t = threadIdx.x;
  const int l = t & 63;
  const int w = t >> 6;                  // wave id = d-quarter
  const int rg = l >> 2;                 // 16 rows, 1 per 4-lane group
  const int kg = l & 3;                  // 4 k-groups x 8 k
  const int m0 = blockIdx.x * 16;
  const int r = m0 + rg;

  const float* xp = x + (size_t)r * DD + w * 256;

  float acc[8];
#pragma unroll
  for (int k = 0; k < 8; ++k) acc[k] = 0.f;

  float4 xa = *(const float4*)(xp);

  // prefetch W chunk 0 into registers
  const float4* Wg4 = (const float4*)(W) + (size_t)w * 2048;  // wave's d-slice
  float4 pw[4];
#pragma unroll
  for (int i = 0; i < 4; ++i) pw[i] = Wg4[i * 64 + l];

#pragma unroll 1
  for (int c = 0; c < 8; ++c) {
    // ---- commit this wave's staged 32-d W chunk (4 KB) to its LDS region --
#pragma unroll
    for (int i = 0; i < 4; ++i) Ls4[w * 256 + i * 64 + l] = pw[i];
    // wave-local write->read: compiler inserts lgkmcnt wait; no barrier.

    // ---- register-prefetch next chunk (hides L2 latency under compute) ----
    if (c < 7) {
#pragma unroll
      for (int i = 0; i < 4; ++i) pw[i] = Wg4[(c + 1) * 256 + i * 64 + l];
    }

#pragma unroll
    for (int gg = 0; gg < 8; ++gg) {
      const int dd = c * 32 + gg * 4;
      int nd = dd + 4; if (nd > 252) nd = 252;   // clamp: last group reloads
      float4 xb = *(const float4*)(xp + nd);
#pragma unroll
      for (int d2 = 0; d2 < 4; ++d2) {
        const int wb = w * 256 + (gg * 4 + d2) * 8 + kg * 2;
        float4 wlo = Ls4[wb];        // 4 distinct addrs, broadcast to 16 lanes
        float4 whi = Ls4[wb + 1];
        const float x0 = ((const float*)&xa)[d2];
        acc[0] = fmaf(x0, wlo.x, acc[0]); acc[1] = fmaf(x0, wlo.y, acc[1]);
        acc[2] = fmaf(x0, wlo.z, acc[2]); acc[3] = fmaf(x0, wlo.w, acc[3]);
        acc[4] = fmaf(x0, whi.x, acc[4]); acc[5] = fmaf(x0, whi.y, acc[5]);
        acc[6] = fmaf(x0, whi.z, acc[6]); acc[7] = fmaf(x0, whi.w, acc[7]);
      }
      xa = xb;
    }
  }

  // ---- cross-quarter reduce through LDS (reuses W regions) ----
  __syncthreads();
  Ls4[w * 128 + rg * 8 + kg * 2] =
      make_float4(acc[0], acc[1], acc[2], acc[3]);
  Ls4[w * 128 + rg * 8 + kg * 2 + 1] =
      make_float4(acc[4], acc[5], acc[6], acc[7]);
  __syncthreads();
  if (t < 128) {
    const int rr = t >> 3;         // 16 rows
    const int kc = t & 7;          // 8 float4 per row
    float4 s = Ls4[rr * 8 + kc];
#pragma unroll
    for (int q = 1; q < 4; ++q) {
      float4 a = Ls4[q * 128 + rr * 8 + kc];
      s.x += a.x; s.y += a.y; s.z += a.z; s.w += a.w;
    }
    float4 bv = *(const float4*)(bias + kc * 4);
    float4 e;
    e.x = __expf(s.x + bv.x); e.y = __expf(s.y + bv.y);
    e.z = __expf(s.z + bv.z); e.w = __expf(s.w + bv.w);
    ((float4*)(F + (size_t)(m0 + rr) * KK))[kc] = e;
  }
}

// ---------------------------------------------------------------------------
// Kernel 2: segmented scaled linear-domain forward/backward recursions.
// (unchanged — correct, off the critical path)
// ---------------------------------------------------------------------------
__global__ __launch_bounds__(64) void scan_kernel(
    const float* __restrict__ F, const float* __restrict__ U,
    float* __restrict__ A, float* __restrict__ Bw) {
  __shared__ __align__(16) float cur[KK];
  const int l = threadIdx.x;
  const int kk = l & 31;
  const int h = l >> 5;
  const int seg = blockIdx.x & 15;
  const int b = (blockIdx.x >> 4) & 63;
  const int dir = blockIdx.x >> 10;

  const float* Fb = F + (size_t)b * TT * KK;
  float V[16];

  if (dir == 0) {
    float* Ab = A + (size_t)b * TT * KK;
#pragma unroll
    for (int j = 0; j < 16; ++j) V[j] = __expf(U[(h * 16 + j) * KK + kk]);
    const int lo = seg * 32, hi = seg * 32 + 31;
    const int t0 = (seg == 0) ? 0 : lo - 17;
    float a = Fb[t0 * KK + kk];
    cur[kk] = a;
    if (seg == 0 && l < 32) Ab[l] = a;
    __builtin_amdgcn_wave_barrier();

#define FSTEP(fv, tcur)                                                     \
    {                                                                       \
      const float4* c4 = (const float4*)cur;                                \
      float4 y0 = c4[h*4+0], y1 = c4[h*4+1], y2 = c4[h*4+2], y3 = c4[h*4+3];\
      float r = __builtin_amdgcn_rcpf(rfl(y0.x));                           \
      float s0 = fmaf(y0.x, V[0],  fmaf(y0.y, V[1],                         \
                 fmaf(y0.z, V[2],  y0.w * V[3])));                          \
      float s1 = fmaf(y1.x, V[4],  fmaf(y1.y, V[5],                         \
                 fmaf(y1.z, V[6],  y1.w * V[7])));                          \
      float s2 = fmaf(y2.x, V[8],  fmaf(y2.y, V[9],                         \
                 fmaf(y2.z, V[10], y2.w * V[11])));                         \
      float s3 = fmaf(y3.x, V[12], fmaf(y3.y, V[13],                        \
                 fmaf(y3.z, V[14], y3.w * V[15])));                         \
      float s = (s0 + s1) + (s2 + s3);                                      \
      s += __shfl_xor(s, 32);                                               \
      a = s * ((fv) * r);                                                   \
      cur[kk] = a;                                                          \
      __builtin_amdgcn_wave_barrier();                                      \
      if ((tcur) >= lo && l < 32) Ab[(tcur) * KK + l] = a;                  \
    }

    int t = t0 + 1;
    float f0 = Fb[t * KK + kk],       f1 = Fb[(t + 1) * KK + kk];
    float f2 = Fb[(t + 2) * KK + kk], f3 = Fb[(t + 3) * KK + kk];
    for (; t + 3 <= hi; t += 4) {
      int tn = t + 4;
      int u0 = tn     > hi ? hi : tn;
      int u1 = tn + 1 > hi ? hi : tn + 1;
      int u2 = tn + 2 > hi ? hi : tn + 2;
      int u3 = tn + 3 > hi ? hi : tn + 3;
      float n0 = Fb[u0 * KK + kk], n1 = Fb[u1 * KK + kk];
      float n2 = Fb[u2 * KK + kk], n3 = Fb[u3 * KK + kk];
      FSTEP(f0, t); FSTEP(f1, t + 1); FSTEP(f2, t + 2); FSTEP(f3, t + 3);
      f0 = n0; f1 = n1; f2 = n2; f3 = n3;
    }
    if (t <= hi) { FSTEP(f0, t); ++t; }
    if (t <= hi) { FSTEP(f1, t); ++t; }
    if (t <= hi) { FSTEP(f2, t); ++t; }
#undef FSTEP
  } else {
    const int b2 = b;
    float* Bb = Bw + (size_t)b2 * TT * KK;
#pragma unroll
    for (int j = 0; j < 16; ++j) V[j] = __expf(U[kk * KK + h * 16 + j]);
    const int lo = seg * 32;
    const int hs = seg * 32 + 31;
    const int t1 = (seg == 15) ? (TT - 1) : (lo + 48);
    float g = Fb[t1 * KK + kk];
    cur[kk] = g;
    if (seg == 15 && l < 32) Bb[(TT - 1) * KK + l] = 1.0f;
    __builtin_amdgcn_wave_barrier();

#define BSTEP(fv, tcur)                                                     \
    {                                                                       \
      const float4* c4 = (const float4*)cur;                                \
      float4 y0 = c4[h*4+0], y1 = c4[h*4+1], y2 = c4[h*4+2], y3 = c4[h*4+3];\
      float r = __builtin_amdgcn_rcpf(rfl(y0.x));                           \
      float s0 = fmaf(y0.x, V[0],  fmaf(y0.y, V[1],                         \
                 fmaf(y0.z, V[2],  y0.w * V[3])));                          \
      float s1 = fmaf(y1.x, V[4],  fmaf(y1.y, V[5],                         \
                 fmaf(y1.z, V[6],  y1.w * V[7])));                          \
      float s2 = fmaf(y2.x, V[8],  fmaf(y2.y, V[9],                         \
                 fmaf(y2.z, V[10], y2.w * V[11])));                         \
      float s3 = fmaf(y3.x, V[12], fmaf(y3.y, V[13],                        \
                 fmaf(y3.z, V[14], y3.w * V[15])));                         \
      float s = (s0 + s1) + (s2 + s3);                                      \
      s += __shfl_xor(s, 32);                                               \
      float bnew = s * r;                                                   \
      g = bnew * (fv);                                                      \
      cur[kk] = g;                                                          \
      __builtin_amdgcn_wave_barrier();                                      \
      if ((tcur) <= hs && l < 32) Bb[(tcur) * KK + l] = bnew;               \
    }

    int t = t1 - 1;
    float f0 = Fb[t * KK + kk],       f1 = Fb[(t - 1) * KK + kk];
    float f2 = Fb[(t - 2) * KK + kk], f3 = Fb[(t - 3) * KK + kk];
    for (; t - 3 >= lo; t -= 4) {
      int tn = t - 4;
      int u0 = tn     < 0 ? 0 : tn;
      int u1 = tn - 1 < 0 ? 0 : tn - 1;
      int u2 = tn - 2 < 0 ? 0 : tn - 2;
      int u3 = tn - 3 < 0 ? 0 : tn - 3;
      float n0 = Fb[u0 * KK + kk], n1 = Fb[u1 * KK + kk];
      float n2 = Fb[u2 * KK + kk], n3 = Fb[u3 * KK + kk];
      BSTEP(f0, t); BSTEP(f1, t - 1); BSTEP(f2, t - 2); BSTEP(f3, t - 3);
      f0 = n0; f1 = n1; f2 = n2; f3 = n3;
    }
    if (t >= lo) { BSTEP(f0, t); --t; }
    if (t >= lo) { BSTEP(f1, t); --t; }
    if (t >= lo) { BSTEP(f2, t); --t; }
#undef BSTEP
  }
}

// ---------------------------------------------------------------------------
// Kernel 3: marginals.  out[m,k] = A[m,k]*B[m,k] / sum_k' A[m,k']*B[m,k'].
// ---------------------------------------------------------------------------
__global__ __launch_bounds__(256) void combine_kernel(
    const float* __restrict__ Bw, float* __restrict__ out) {
  size_t i = (size_t)blockIdx.x * 256 + threadIdx.x;
  float p = out[i] * Bw[i];
  float ssum = p;
  ssum += __shfl_xor(ssum, 1);
  ssum += __shfl_xor(ssum, 2);
  ssum += __shfl_xor(ssum, 4);
  ssum += __shfl_xor(ssum, 8);
  ssum += __shfl_xor(ssum, 16);
  out[i] = p / ssum;
}

extern "C" void kernel_launch(void* const* d_in, const int* in_sizes, int n_in,
                              void* d_out, int out_size, void* d_ws, size_t ws_size,
                              hipStream_t stream) {
  const float* x = (const float*)d_in[0];   // [B,T,D]
  const float* W = (const float*)d_in[1];   // [D,K]
  const float* U = (const float*)d_in[2];   // [K,K]
  const float* b = (const float*)d_in[3];   // [K]
  float* out = (float*)d_out;               // [B,T,K] — doubles as A scratch
  float* F = (float*)d_ws;                  // exp(emissions), [B*T, K] (4 MB)
  float* Bw = F + (size_t)BB * TT * KK;     // backward messages    (4 MB)

  emit_kernel<<<2048, 256, 0, stream>>>(x, W, b, F);
  scan_kernel<<<2048, 64, 0, stream>>>(F, U, out, Bw);
  combine_kernel<<<(BB * TT * KK) / 256, 256, 0, stream>>>(Bw, out);
}

// Round 2
// 237.839 us; speedup vs baseline: 1.3001x; 1.3001x over previous
//
#include <hip/hip_runtime.h>
#include <stdint.h>

#define TT 512
#define BB 64
#define DD 1024
#define KK 32

__device__ __forceinline__ float rfl(float v) {
  return __int_as_float(__builtin_amdgcn_readfirstlane(__float_as_int(v)));
}

// Direct global->LDS copy, 16 B per lane.  LDS dest is wave-uniform base;
// HW writes base + lane*16 (linear lane order).  Zero VGPR staging cost.
__device__ __forceinline__ void gload_lds16(const float4* g, float4* l) {
  __builtin_amdgcn_global_load_lds(
      (const __attribute__((address_space(1))) uint32_t*)g,
      (__attribute__((address_space(3))) uint32_t*)l, 16, 0, 0);
}

// ---------------------------------------------------------------------------
// Kernel 1: emission.  F[m,k] = exp( x[m,:] @ W[:,k] + b[k] ).
// r7: keep r6's occupancy tiling (grid 2048, 16 rows/block, 16 KB LDS,
// 8 blocks/CU -> 32 waves/CU) but stage W via global_load_lds instead of
// register prefetch.  r6 post-mortem: __launch_bounds__(256,8) caps VGPR
// at 64; the pw[4]+double-buffer structure needed ~75 -> spilled 208 MB
// to scratch (WRITE_SIZE counter), emit 156us.  global_load_lds uses no
// VGPRs: live set is acc[8]+xa/xb+pointers ~35.  Per-chunk vmcnt(0) stall
// (~L2 latency) is hidden by 8 waves/SIMD TLP.  Wave-local staging, no
// barrier: all chunk-c ds_reads are consumed (lgkmcnt-drained) before
// chunk c+1 staging issues; LDS write lands >=200cy after issue.
// ---------------------------------------------------------------------------
__global__ __launch_bounds__(256, 8) void emit_kernel(
    const float* __restrict__ x, const float* __restrict__ W,
    const float* __restrict__ bias, float* __restrict__ F) {
  __shared__ float4 Ls4[1024];           // 16 KB: 4 waves x 256 f4 W chunk
  const int t = threadIdx.x;
  const int l = t & 63;
  const int w = t >> 6;                  // wave id = d-quarter
  const int rg = l >> 2;                 // 16 rows, 1 per 4-lane group
  const int kg = l & 3;                  // 4 k-groups x 8 k
  const int m0 = blockIdx.x * 16;
  const int r = m0 + rg;

  const float* xp = x + (size_t)r * DD + w * 256;

  float acc[8];
#pragma unroll
  for (int k = 0; k < 8; ++k) acc[k] = 0.f;

  float4 xa = *(const float4*)(xp);

  const float4* Wg4 = (const float4*)(W) + (size_t)w * 2048;  // wave's d-slice
  float4* Lw = &Ls4[w * 256];            // wave's LDS region (wave-uniform)

#pragma unroll 1
  for (int c = 0; c < 8; ++c) {
    // ---- stage this wave's 32-d W chunk (4 KB) straight into LDS ----------
#pragma unroll
    for (int i = 0; i < 4; ++i)
      gload_lds16(Wg4 + c * 256 + i * 64 + l, Lw + i * 64);
    asm volatile("s_waitcnt vmcnt(0)" ::: "memory");

#pragma unroll
    for (int gg = 0; gg < 8; ++gg) {
      const int dd = c * 32 + gg * 4;
      int nd = dd + 4; if (nd > 252) nd = 252;   // clamp: last group reloads
      float4 xb = *(const float4*)(xp + nd);
#pragma unroll
      for (int d2 = 0; d2 < 4; ++d2) {
        const int wb = w * 256 + (gg * 4 + d2) * 8 + kg * 2;
        float4 wlo = Ls4[wb];        // 4 distinct addrs, broadcast to 16 lanes
        float4 whi = Ls4[wb + 1];
        const float x0 = ((const float*)&xa)[d2];
        acc[0] = fmaf(x0, wlo.x, acc[0]); acc[1] = fmaf(x0, wlo.y, acc[1]);
        acc[2] = fmaf(x0, wlo.z, acc[2]); acc[3] = fmaf(x0, wlo.w, acc[3]);
        acc[4] = fmaf(x0, whi.x, acc[4]); acc[5] = fmaf(x0, whi.y, acc[5]);
        acc[6] = fmaf(x0, whi.z, acc[6]); acc[7] = fmaf(x0, whi.w, acc[7]);
      }
      xa = xb;
    }
  }

  // ---- cross-quarter reduce through LDS (reuses W regions) ----
  __syncthreads();
  Ls4[w * 128 + rg * 8 + kg * 2] =
      make_float4(acc[0], acc[1], acc[2], acc[3]);
  Ls4[w * 128 + rg * 8 + kg * 2 + 1] =
      make_float4(acc[4], acc[5], acc[6], acc[7]);
  __syncthreads();
  if (t < 128) {
    const int rr = t >> 3;         // 16 rows
    const int kc = t & 7;          // 8 float4 per row
    float4 s = Ls4[rr * 8 + kc];
#pragma unroll
    for (int q = 1; q < 4; ++q) {
      float4 a = Ls4[q * 128 + rr * 8 + kc];
      s.x += a.x; s.y += a.y; s.z += a.z; s.w += a.w;
    }
    float4 bv = *(const float4*)(bias + kc * 4);
    float4 e;
    e.x = __expf(s.x + bv.x); e.y = __expf(s.y + bv.y);
    e.z = __expf(s.z + bv.z); e.w = __expf(s.w + bv.w);
    ((float4*)(F + (size_t)(m0 + rr) * KK))[kc] = e;
  }
}

// ---------------------------------------------------------------------------
// Kernel 2: segmented scaled linear-domain forward/backward recursions.
// (unchanged — correct, off the critical path)
// ---------------------------------------------------------------------------
__global__ __launch_bounds__(64) void scan_kernel(
    const float* __restrict__ F, const float* __restrict__ U,
    float* __restrict__ A, float* __restrict__ Bw) {
  __shared__ __align__(16) float cur[KK];
  const int l = threadIdx.x;
  const int kk = l & 31;
  const int h = l >> 5;
  const int seg = blockIdx.x & 15;
  const int b = (blockIdx.x >> 4) & 63;
  const int dir = blockIdx.x >> 10;

  const float* Fb = F + (size_t)b * TT * KK;
  float V[16];

  if (dir == 0) {
    float* Ab = A + (size_t)b * TT * KK;
#pragma unroll
    for (int j = 0; j < 16; ++j) V[j] = __expf(U[(h * 16 + j) * KK + kk]);
    const int lo = seg * 32, hi = seg * 32 + 31;
    const int t0 = (seg == 0) ? 0 : lo - 17;
    float a = Fb[t0 * KK + kk];
    cur[kk] = a;
    if (seg == 0 && l < 32) Ab[l] = a;
    __builtin_amdgcn_wave_barrier();

#define FSTEP(fv, tcur)                                                     \
    {                                                                       \
      const float4* c4 = (const float4*)cur;                                \
      float4 y0 = c4[h*4+0], y1 = c4[h*4+1], y2 = c4[h*4+2], y3 = c4[h*4+3];\
      float r = __builtin_amdgcn_rcpf(rfl(y0.x));                           \
      float s0 = fmaf(y0.x, V[0],  fmaf(y0.y, V[1],                         \
                 fmaf(y0.z, V[2],  y0.w * V[3])));                          \
      float s1 = fmaf(y1.x, V[4],  fmaf(y1.y, V[5],                         \
                 fmaf(y1.z, V[6],  y1.w * V[7])));                          \
      float s2 = fmaf(y2.x, V[8],  fmaf(y2.y, V[9],                         \
                 fmaf(y2.z, V[10], y2.w * V[11])));                         \
      float s3 = fmaf(y3.x, V[12], fmaf(y3.y, V[13],                        \
                 fmaf(y3.z, V[14], y3.w * V[15])));                         \
      float s = (s0 + s1) + (s2 + s3);                                      \
      s += __shfl_xor(s, 32);                                               \
      a = s * ((fv) * r);                                                   \
      cur[kk] = a;                                                          \
      __builtin_amdgcn_wave_barrier();                                      \
      if ((tcur) >= lo && l < 32) Ab[(tcur) * KK + l] = a;                  \
    }

    int t = t0 + 1;
    float f0 = Fb[t * KK + kk],       f1 = Fb[(t + 1) * KK + kk];
    float f2 = Fb[(t + 2) * KK + kk], f3 = Fb[(t + 3) * KK + kk];
    for (; t + 3 <= hi; t += 4) {
      int tn = t + 4;
      int u0 = tn     > hi ? hi : tn;
      int u1 = tn + 1 > hi ? hi : tn + 1;
      int u2 = tn + 2 > hi ? hi : tn + 2;
      int u3 = tn + 3 > hi ? hi : tn + 3;
      float n0 = Fb[u0 * KK + kk], n1 = Fb[u1 * KK + kk];
      float n2 = Fb[u2 * KK + kk], n3 = Fb[u3 * KK + kk];
      FSTEP(f0, t); FSTEP(f1, t + 1); FSTEP(f2, t + 2); FSTEP(f3, t + 3);
      f0 = n0; f1 = n1; f2 = n2; f3 = n3;
    }
    if (t <= hi) { FSTEP(f0, t); ++t; }
    if (t <= hi) { FSTEP(f1, t); ++t; }
    if (t <= hi) { FSTEP(f2, t); ++t; }
#undef FSTEP
  } else {
    const int b2 = b;
    float* Bb = Bw + (size_t)b2 * TT * KK;
#pragma unroll
    for (int j = 0; j < 16; ++j) V[j] = __expf(U[kk * KK + h * 16 + j]);
    const int lo = seg * 32;
    const int hs = seg * 32 + 31;
    const int t1 = (seg == 15) ? (TT - 1) : (lo + 48);
    float g = Fb[t1 * KK + kk];
    cur[kk] = g;
    if (seg == 15 && l < 32) Bb[(TT - 1) * KK + l] = 1.0f;
    __builtin_amdgcn_wave_barrier();

#define BSTEP(fv, tcur)                                                     \
    {                                                                       \
      const float4* c4 = (const float4*)cur;                                \
      float4 y0 = c4[h*4+0], y1 = c4[h*4+1], y2 = c4[h*4+2], y3 = c4[h*4+3];\
      float r = __builtin_amdgcn_rcpf(rfl(y0.x));                           \
      float s0 = fmaf(y0.x, V[0],  fmaf(y0.y, V[1],                         \
                 fmaf(y0.z, V[2],  y0.w * V[3])));                          \
      float s1 = fmaf(y1.x, V[4],  fmaf(y1.y, V[5],                         \
                 fmaf(y1.z, V[6],  y1.w * V[7])));                          \
      float s2 = fmaf(y2.x, V[8],  fmaf(y2.y, V[9],                         \
                 fmaf(y2.z, V[10], y2.w * V[11])));                         \
      float s3 = fmaf(y3.x, V[12], fmaf(y3.y, V[13],                        \
                 fmaf(y3.z, V[14], y3.w * V[15])));                         \
      float s = (s0 + s1) + (s2 + s3);                                      \
      s += __shfl_xor(s, 32);                                               \
      float bnew = s * r;                                                   \
      g = bnew * (fv);                                                      \
      cur[kk] = g;                                                          \
      __builtin_amdgcn_wave_barrier();                                      \
      if ((tcur) <= hs && l < 32) Bb[(tcur) * KK + l] = bnew;               \
    }

    int t = t1 - 1;
    float f0 = Fb[t * KK + kk],       f1 = Fb[(t - 1) * KK + kk];
    float f2 = Fb[(t - 2) * KK + kk], f3 = Fb[(t - 3) * KK + kk];
    for (; t - 3 >= lo; t -= 4) {
      int tn = t - 4;
      int u0 = tn     < 0 ? 0 : tn;
      int u1 = tn - 1 < 0 ? 0 : tn - 1;
      int u2 = tn - 2 < 0 ? 0 : tn - 2;
      int u3 = tn - 3 < 0 ? 0 : tn - 3;
      float n0 = Fb[u0 * KK + kk], n1 = Fb[u1 * KK + kk];
      float n2 = Fb[u2 * KK + kk], n3 = Fb[u3 * KK + kk];
      BSTEP(f0, t); BSTEP(f1, t - 1); BSTEP(f2, t - 2); BSTEP(f3, t - 3);
      f0 = n0; f1 = n1; f2 = n2; f3 = n3;
    }
    if (t >= lo) { BSTEP(f0, t); --t; }
    if (t >= lo) { BSTEP(f1, t); --t; }
    if (t >= lo) { BSTEP(f2, t); --t; }
#undef BSTEP
  }
}

// ---------------------------------------------------------------------------
// Kernel 3: marginals.  out[m,k] = A[m,k]*B[m,k] / sum_k' A[m,k']*B[m,k'].
// ---------------------------------------------------------------------------
__global__ __launch_bounds__(256) void combine_kernel(
    const float* __restrict__ Bw, float* __restrict__ out) {
  size_t i = (size_t)blockIdx.x * 256 + threadIdx.x;
  float p = out[i] * Bw[i];
  float ssum = p;
  ssum += __shfl_xor(ssum, 1);
  ssum += __shfl_xor(ssum, 2);
  ssum += __shfl_xor(ssum, 4);
  ssum += __shfl_xor(ssum, 8);
  ssum += __shfl_xor(ssum, 16);
  out[i] = p / ssum;
}

extern "C" void kernel_launch(void* const* d_in, const int* in_sizes, int n_in,
                              void* d_out, int out_size, void* d_ws, size_t ws_size,
                              hipStream_t stream) {
  const float* x = (const float*)d_in[0];   // [B,T,D]
  const float* W = (const float*)d_in[1];   // [D,K]
  const float* U = (const float*)d_in[2];   // [K,K]
  const float* b = (const float*)d_in[3];   // [K]
  float* out = (float*)d_out;               // [B,T,K] — doubles as A scratch
  float* F = (float*)d_ws;                  // exp(emissions), [B*T, K] (4 MB)
  float* Bw = F + (size_t)BB * TT * KK;     // backward messages    (4 MB)

  emit_kernel<<<2048, 256, 0, stream>>>(x, W, b, F);
  scan_kernel<<<2048, 64, 0, stream>>>(F, U, out, Bw);
  combine_kernel<<<(BB * TT * KK) / 256, 256, 0, stream>>>(Bw, out);
}